// Round 9
// baseline (270.348 us; speedup 1.0000x reference)
//
#include <hip/hip_runtime.h>
#include <math.h>

#define HH 256
#define WW 256
#define BC 512   // B*C = 8*64
#define QN 100
#define RBAND 16 // output rows per wave

// ---------------------------------------------------------------------------
// Kernel 1: per-(b,c) 18x100 GEMM + q output + derived conv coefficients.
// coef layout per bc (stride 32 floats): [0..8]=former, [9..17]=wk,
// [18..26]=|wk|, [27..29]=column sums of wk (kept for layout compat).
// ---------------------------------------------------------------------------
__global__ __launch_bounds__(128) void prep_kernel(
    const float* __restrict__ query,   // (100, 8, 64) = (100, 512)
    const float* __restrict__ Wl,      // (18, 100)
    const float* __restrict__ bl,      // (18,)
    const float* __restrict__ Wd,      // (100, 18)
    const float* __restrict__ bd,      // (100,)
    float* __restrict__ qout,          // (100, 512) region of d_out
    float* __restrict__ coef)          // (512, 32) in d_ws
{
    const int bc = blockIdx.x;
    const int t  = threadIdx.x;
    __shared__ float qcol[QN];
    __shared__ float c18[18];

    if (t < QN) qcol[t] = query[t * BC + bc];
    __syncthreads();

    if (t < 18) {
        float acc = bl[t];
        const float* wrow = Wl + t * QN;
        #pragma unroll 4
        for (int qi = 0; qi < QN; ++qi) acc += qcol[qi] * wrow[qi];
        c18[t] = acc;
    }
    __syncthreads();

    if (t < QN) {
        float acc = bd[t];
        const float* wrow = Wd + t * 18;
        #pragma unroll
        for (int k = 0; k < 18; ++k) acc += c18[k] * wrow[k];
        qout[t * BC + bc] = acc;   // q.transpose(2,0,1) layout
    }

    if (t < 18) {
        coef[bc * 32 + t] = c18[t];                      // former / wk
    } else if (t < 27) {
        coef[bc * 32 + t] = fabsf(c18[t - 9]);           // |wk|
    } else if (t < 30) {
        int j = t - 27;
        coef[bc * 32 + t] = c18[9 + j] + c18[12 + j] + c18[15 + j]; // colsum
    }
}

// ---------------------------------------------------------------------------
// Kernel 2: LDS-free streaming stencil, RING-OF-8 with IN-PLACE loads.
// One wave64 spans the full 256-col image width (4 cols/lane); each wave
// streams a 16-row band.
//   v[8][6] : value rows, slot = row & 7 (r0 % 8 == 0).  Loads are issued
//             DIRECTLY into the slot whose old row died 3 iterations ago —
//             distance-3 pipelining with no raw buffer and no per-row copy
//             (round-8 post-mortem: the 6-mov FINISH copy + per-row guards
//             were pure bookkeeping, ~2.5x the irreducible VALU count).
//   d[4][6] : diff rows, slot = row & 3.
//   yt2[2][4]: former-conv reuse (COMPD(h) saves yt, OUTROW(h) consumes).
// Interior bands (14 of 16): fully-unrolled 16-row straight-line body with
// ZERO branches and no row-bound compares.  Edge bands: compact guarded
// rolled loop (perf-irrelevant, 2/16 of waves).
// Iteration j (h = r0+j): MASK row h+2 (loads issued at j-3; in-place 2
// cndmasks) | ISSUE row h+5 into its dead slot | COMPD diff(h+1) (+yt) |
// OUTROW(h) (plain store -> L2; stores stay newer in the vmcnt FIFO than
// any waited-on loads, 4-row slack).
// ---------------------------------------------------------------------------
__global__ __launch_bounds__(256, 4) void fused_kernel(
    const float* __restrict__ value,   // (512, 256, 256)
    const float* __restrict__ coef,    // (512, 32)
    float* __restrict__ yout)          // (512, 256, 256) region of d_out
{
    const int bc   = blockIdx.z;
    const int wave = threadIdx.x >> 6;
    const int lane = threadIdx.x & 63;
    const int band = blockIdx.x * 4 + wave;
    const int r0   = band * RBAND;
    const int x4   = lane << 2;

    const bool l0  = (lane == 0);
    const bool l63 = (lane == 63);
    // clamped halo columns (in-row; masked to 0 at MASK/FINISH)
    const int xl = l0  ? 0   : x4 - 1;
    const int xr = l63 ? 255 : x4 + 4;

    // coefficients: block-uniform address -> scalar (SGPR) loads
    const float* cp = coef + bc * 32;
    float fco[9], awk[9], wk6[6];
    #pragma unroll
    for (int i = 0; i < 9; ++i) { fco[i] = cp[i]; awk[i] = cp[18 + i]; }
    wk6[0] = cp[9];  wk6[1] = cp[10]; wk6[2] = cp[11];
    wk6[3] = cp[15]; wk6[4] = cp[16]; wk6[5] = cp[17];

    const float* vbase = value + (size_t)bc * (HH * WW);
    float*       obase = yout  + (size_t)bc * (HH * WW);

    float v[8][6];      // value rows, slot = row & 7, cols x4-1 .. x4+4
    float d[4][6];      // diff rows,  slot = row & 3, cols x4-1 .. x4+4
    float yt2[2][4];    // former-conv reuse, slot = row & 1

    // tree-form 9-term dot: 3 independent 3-FMA chains, then 2 adds
    auto DOT9 = [](const float* f, const float* ra, const float* rb,
                   const float* rc, int c) -> float {
        float s0 = fmaf(f[2], ra[c + 2], fmaf(f[1], ra[c + 1], f[0] * ra[c]));
        float s1 = fmaf(f[5], rb[c + 2], fmaf(f[4], rb[c + 1], f[3] * rb[c]));
        float s2 = fmaf(f[8], rc[c + 2], fmaf(f[7], rc[c + 1], f[6] * rc[c]));
        return (s0 + s1) + s2;
    };

    // issue row r's loads straight into ring slot s (no wait; consumed 3
    // iterations later).  chk=false -> unconditional (interior band).
    auto ISSUE = [&](int r, int s, bool chk) {
        if (!chk || (unsigned)r < HH) {
            const float* rowp = vbase + r * WW;
            const float4 q = *(const float4*)(rowp + x4);
            v[s][0] = rowp[xl];
            v[s][1] = q.x; v[s][2] = q.y; v[s][3] = q.z; v[s][4] = q.w;
            v[s][5] = rowp[xr];
        }
        // chk && out-of-range: slot left stale; MASK zeroes it.
    };

    // retire slot s in place: column-edge mask (2 cndmasks); zero OOR rows.
    auto MASK = [&](int r, int s, bool chk) {
        if (chk && (unsigned)r >= HH) {
            #pragma unroll
            for (int m = 0; m < 6; ++m) v[s][m] = 0.f;
        } else {
            if (l0)  v[s][0] = 0.f;
            if (l63) v[s][5] = 0.f;
        }
    };

    // diff row r from value rows r-1 (va), r (vb), r+1 (vc); saves yt(r)
    auto COMPD = [&](int r, const float* va, const float* vb, const float* vc,
                     float* drow, float* ytr, bool chk) {
        if (!chk || (unsigned)r < HH) {
            float d4[4];
            #pragma unroll
            for (int c = 0; c < 4; ++c) {
                float yt = DOT9(fco, va, vb, vc, c);
                ytr[c] = yt;
                float e = vb[c + 1] - yt;
                d4[c] = __expf(-e * e);
            }
            drow[1] = d4[0]; drow[2] = d4[1]; drow[3] = d4[2]; drow[4] = d4[3];
            float left  = __shfl_up(d4[3], 1);
            float right = __shfl_down(d4[0], 1);
            drow[0] = l0  ? 0.f : left;
            drow[5] = l63 ? 0.f : right;
        } else {
            #pragma unroll
            for (int m = 0; m < 6; ++m) drow[m] = 0.f;
        }
    };

    // output row h (always in-image); yt(h) precomputed by COMPD(h)
    auto OUTROW = [&](int h, const float* vp, const float* vq, const float* vs,
                      const float* dp, const float* dq, const float* ds,
                      const float* ytr) {
        float dv0[6], dv2[6];
        #pragma unroll
        for (int m = 0; m < 6; ++m) {
            float mid = dq[m] * vq[m];
            dv0[m] = fmaf(dp[m], vp[m], -mid);
            dv2[m] = fmaf(ds[m], vs[m], -mid);
        }
        float4 o;
        #pragma unroll
        for (int c = 0; c < 4; ++c) {
            float y0 = fmaf(awk[2], dp[c + 2],
                       fmaf(awk[1], dp[c + 1], fmaf(awk[0], dp[c], 1e-10f)));
            float y1 = fmaf(awk[5], dq[c + 2],
                       fmaf(awk[4], dq[c + 1], awk[3] * dq[c]));
            float y2 = fmaf(awk[8], ds[c + 2],
                       fmaf(awk[7], ds[c + 1], awk[6] * ds[c]));
            float yd9 = (y0 + y1) + y2;
            float n0 = fmaf(wk6[2], dv0[c + 2],
                       fmaf(wk6[1], dv0[c + 1], wk6[0] * dv0[c]));
            float n1 = fmaf(wk6[5], dv2[c + 2],
                       fmaf(wk6[4], dv2[c + 1], wk6[3] * dv2[c]));
            float num = n0 + n1;
            (&o.x)[c] = fmaf(-num, __builtin_amdgcn_rcpf(yd9), ytr[c]);
        }
        *(float4*)(obase + h * WW + x4) = o;
    };

    if (r0 >= 2 && r0 + RBAND + 2 <= HH) {
        // ================= interior fast path: branch-free ==================
        // prologue: rows r0-2..r0+1 into slots 6,7,0,1; diff r0-1, r0;
        // rows r0+2..r0+4 in flight (slots 2,3,4).
        ISSUE(r0 - 2, 6, false); MASK(r0 - 2, 6, false);
        ISSUE(r0 - 1, 7, false); MASK(r0 - 1, 7, false);
        ISSUE(r0,     0, false); MASK(r0,     0, false);
        ISSUE(r0 + 1, 1, false); MASK(r0 + 1, 1, false);
        COMPD(r0 - 1, v[6], v[7], v[0], d[3], yt2[1], false);
        COMPD(r0,     v[7], v[0], v[1], d[0], yt2[0], false);
        ISSUE(r0 + 2, 2, false);
        ISSUE(r0 + 3, 3, false);
        ISSUE(r0 + 4, 4, false);

        // 16 rows fully unrolled; all ring indices compile-time.
        // iter j (h=r0+j): MASK h+2 | ISSUE h+5 (skip once past r0+17) |
        // COMPD h+1 | OUTROW h.
        #pragma unroll
        for (int half = 0; half < 2; ++half) {
            const int hb = r0 + 8 * half;
            #pragma unroll
            for (int j4 = 0; j4 < 8; ++j4) {
                const int h = hb + j4;
                MASK(h + 2, (j4 + 2) & 7, false);
                if (half == 0 || j4 < 5)                 // compile-time fold
                    ISSUE(h + 5, (j4 + 5) & 7, false);
                COMPD(h + 1, v[j4], v[(j4 + 1) & 7], v[(j4 + 2) & 7],
                      d[(j4 + 1) & 3], yt2[(j4 + 1) & 1], false);
                OUTROW(h, v[(j4 + 7) & 7], v[j4], v[(j4 + 1) & 7],
                       d[(j4 + 3) & 3], d[j4 & 3], d[(j4 + 1) & 3],
                       yt2[j4 & 1]);
            }
        }
    } else {
        // ================= edge path (bands 0 and 15): guarded ==============
        float raw[6];
        auto ISSUE2 = [&](int r, float* rw) {
            if ((unsigned)r < HH) {
                const float* rowp = vbase + r * WW;
                const float4 q = *(const float4*)(rowp + x4);
                rw[0] = rowp[xl];
                rw[1] = q.x; rw[2] = q.y; rw[3] = q.z; rw[4] = q.w;
                rw[5] = rowp[xr];
            } else {
                #pragma unroll
                for (int m = 0; m < 6; ++m) rw[m] = 0.f;
            }
        };
        auto FINISH2 = [&](const float* rw, float* vr) {
            vr[0] = l0 ? 0.f : rw[0];
            vr[1] = rw[1]; vr[2] = rw[2]; vr[3] = rw[3]; vr[4] = rw[4];
            vr[5] = l63 ? 0.f : rw[5];
        };
        auto LOADV = [&](int r, float* vr) {
            float tmp[6];
            ISSUE2(r, tmp);
            FINISH2(tmp, vr);
        };

        // R5-style mod-4 ring using slots v[0..3]
        LOADV(r0 - 2, v[2]);
        LOADV(r0 - 1, v[3]);
        LOADV(r0,     v[0]);
        LOADV(r0 + 1, v[1]);
        COMPD(r0 - 1, v[2], v[3], v[0], d[3], yt2[1], true);
        COMPD(r0,     v[3], v[0], v[1], d[0], yt2[0], true);
        ISSUE2(r0 + 2, raw);

        for (int io = 0; io < RBAND; io += 4) {
            #pragma unroll
            for (int j4 = 0; j4 < 4; ++j4) {
                const int h = r0 + io + j4;
                const int s = (j4 + 2) & 3;            // slot of row h+2
                FINISH2(raw, v[s]);
                ISSUE2(h + 3, raw);
                COMPD(h + 1, v[j4 & 3], v[(j4 + 1) & 3], v[s],
                      d[(j4 + 1) & 3], yt2[(j4 + 1) & 1], true);
                OUTROW(h, v[(j4 + 3) & 3], v[j4 & 3], v[(j4 + 1) & 3],
                       d[(j4 + 3) & 3], d[j4 & 3], d[(j4 + 1) & 3],
                       yt2[j4 & 1]);
            }
        }
    }
}

// ---------------------------------------------------------------------------
extern "C" void kernel_launch(void* const* d_in, const int* in_sizes, int n_in,
                              void* d_out, int out_size, void* d_ws, size_t ws_size,
                              hipStream_t stream) {
    const float* query = (const float*)d_in[0];   // (100,8,64)
    const float* value = (const float*)d_in[1];   // (8,64,256,256)
    // d_in[2..4]: unused scalars
    const float* Wl    = (const float*)d_in[5];   // (18,100)
    const float* bl    = (const float*)d_in[6];   // (18,)
    const float* Wd    = (const float*)d_in[7];   // (100,18)
    const float* bd    = (const float*)d_in[8];   // (100,)

    float* out   = (float*)d_out;
    float* qout  = out;                 // first 100*512 floats
    float* yout  = out + QN * BC;       // then 512*256*256 floats
    float* coef  = (float*)d_ws;        // 512*32 floats = 64 KB

    prep_kernel<<<BC, 128, 0, stream>>>(query, Wl, bl, Wd, bd, qout, coef);

    // 16 bands of 16 rows per image; 4 waves (bands) per block
    dim3 grid(HH / (RBAND * 4), 1, BC);
    fused_kernel<<<grid, 256, 0, stream>>>(value, coef, yout);
}